// Round 13
// baseline (195.178 us; speedup 1.0000x reference)
//
#include <hip/hip_runtime.h>
#include <math.h>

#define DEV __device__ __forceinline__
DEV float leakyf(float v) { return v >= 0.f ? v : 0.01f * v; }
DEV int rfl(int v) { return __builtin_amdgcn_readfirstlane(v); }

struct F4 { float x, y, z, w; };   // natural align 4: legal on any float*

// ---- ws layout (float offsets) ----
#define OFF_XP   0u          // x padded [64][130][130]      1081600
#define OFF_H1P  1081600u    // h1 [64][8][66][66]           2230272
#define OFF_H2P  3311872u    // h2 [64][16][34][34]          1183744
#define OFF_H3   4495616u    // h3 [64][16][32][32]          1048576
#define OFF_D1P  5544192u    // d1 [64][16][34][34]          1183744
#define OFF_D2P  6727936u    // d2 [64][8][66][66]           2230272
#define OFF_IDX  8958208u    // 65536 int32
#define OFF_U    9023744u    // 73728 [k512][tap9][co16]
#define OFF_C2   9097472u    // 512
#define OFF_W4T  9097984u    // 1024 [ci16][d64]
#define OFF_DWT  9099008u    // 9216 [ci64][tap9*16+co16]
#define OFF_LOSS 9108224u    // 1 (+pad)

// ---------- prep: W4T, |c|^2, dw1 transpose, LOSS zero ----------
__global__ void prep_k(const float* __restrict__ ew4, const float* __restrict__ dw1,
                       const float* __restrict__ cb, float* __restrict__ ws)
{
    int b = blockIdx.x, t = threadIdx.x;
    if (b == 0 && t == 0) ws[OFF_LOSS] = 0.f;
    if (b < 4) {                      // W4T: [ci*64+d] = ew4[d][ci]
        int id = b * 256 + t;
        int d = id & 63, ci = id >> 6;
        ws[OFF_W4T + id] = ew4[d * 16 + ci];
    } else if (b < 6) {               // C2
        int k = (b - 4) * 256 + t;
        float s = 0.f;
        #pragma unroll
        for (int d = 0; d < 64; ++d) { float v = cb[k * 64 + d]; s = fmaf(v, v, s); }
        ws[OFF_C2 + k] = s;
    } else {                          // DWT: [ci*144 + tap*16 + co] = dw1[co][ci][tap]
        int id = (b - 6) * 256 + t;
        if (id < 9216) {
            int co = id & 15, tap = (id >> 4) % 9, ci = id / 144;
            ws[OFF_DWT + id] = dw1[(co * 64 + ci) * 9 + tap];
        }
    }
}

// U[k][tap][co] = sum_ci dwT[ci][tap*16+co] * cb[k][ci]
__global__ void uprep_k(const float* __restrict__ dwT, const float* __restrict__ cb,
                        float* __restrict__ U)
{
    int id = blockIdx.x * 256 + threadIdx.x;   // 73728
    int k = id / 144;
    int r = id - k * 144;
    float s = 0.f;
    #pragma unroll
    for (int ci = 0; ci < 64; ++ci)
        s = fmaf(cb[k * 64 + ci], dwT[ci * 144 + r], s);
    U[id] = s;
}

// ---------- halo zeroing + x padding, one kernel ----------
DEV void halo_store(float* base, int plane, int r, int W, int H, long psz)
{
    int row, col;
    if (r < W)          { row = 0;     col = r; }
    else if (r < 2 * W) { row = H - 1; col = r - W; }
    else { int r2 = r - 2 * W; row = 1 + (r2 >> 1); col = (r2 & 1) ? W - 1 : 0; }
    base[plane * psz + row * W + col] = 0.f;
}

__global__ void setup2_k(const float* __restrict__ x, float* __restrict__ ws)
{
    int id = blockIdx.x * 256 + threadIdx.x;       // 1048576
    {
        int ix = id & 127, iy = (id >> 7) & 127, n = id >> 14;
        ws[OFF_XP + (n * 130 + iy + 1) * 130 + ix + 1] = x[id];
    }
    if (id < 33024) {
        halo_store(ws + OFF_XP, id / 516, id % 516, 130, 130, 16900);
    } else if (id < 166144) {
        int i = id - 33024;
        halo_store(ws + OFF_H1P, i / 260, i % 260, 66, 66, 4356);
    } else if (id < 301312) {
        int i = id - 166144;
        halo_store(ws + OFF_H2P, i / 132, i % 132, 34, 34, 1156);
    } else if (id < 436480) {
        int i = id - 301312;
        halo_store(ws + OFF_D1P, i / 132, i % 132, 34, 34, 1156);
    } else if (id < 569600) {
        int i = id - 436480;
        halo_store(ws + OFF_D2P, i / 260, i % 260, 66, 66, 4356);
    }
}

// ---------- e1: 1->8, K4 S2 P1 ----------
__global__ __launch_bounds__(256) void e1p_k(const float* __restrict__ xp,
                                             const float* __restrict__ ew1,
                                             const float* __restrict__ eb1,
                                             float* __restrict__ h1p)
{
    __shared__ float wl[128];
    int t = threadIdx.x;
    if (t < 128) { int co = t & 7, tap = t >> 3; wl[t] = ew1[co * 16 + tap]; }
    __syncthreads();
    int id = blockIdx.x * 256 + t;                 // 262144
    int x = id & 63, y = (id >> 6) & 63, n = id >> 12;
    float acc[8];
    #pragma unroll
    for (int j = 0; j < 8; ++j) acc[j] = eb1[j];
    const float* base = xp + (n * 130 + 2 * y) * 130 + 2 * x;
    #pragma unroll
    for (int ky = 0; ky < 4; ++ky) {
        F4 v = *(const F4*)(base + ky * 130);
        float vv[4] = { v.x, v.y, v.z, v.w };
        #pragma unroll
        for (int kx = 0; kx < 4; ++kx) {
            const float* wp = &wl[(ky * 4 + kx) * 8];
            #pragma unroll
            for (int j = 0; j < 8; ++j) acc[j] = fmaf(vv[kx], wp[j], acc[j]);
        }
    }
    #pragma unroll
    for (int j = 0; j < 8; ++j)
        h1p[((n * 8 + j) * 66 + y + 1) * 66 + x + 1] = leakyf(acc[j]);
}

// ---------- e2: 8->16, K4 S2 P1, COB4 ----------
__global__ __launch_bounds__(256) void e2p_k(const float* __restrict__ h1p,
                                             const float* __restrict__ ew2,
                                             const float* __restrict__ eb2,
                                             float* __restrict__ h2p)
{
    __shared__ float wl[512];
    int t = threadIdx.x;
    int id = blockIdx.x * 256 + t;                 // 262144
    int x = id & 31, y = (id >> 5) & 31;
    int cg = rfl((id >> 10) & 3), n = id >> 12;
    for (int i = t; i < 512; i += 256) {
        int co = i & 3, r = i >> 2;
        int kx = r & 3, ky = (r >> 2) & 3, ci = r >> 4;
        wl[i] = ew2[((cg * 4 + co) * 8 + ci) * 16 + ky * 4 + kx];
    }
    __syncthreads();
    float acc[4];
    #pragma unroll
    for (int j = 0; j < 4; ++j) acc[j] = eb2[cg * 4 + j];
    #pragma unroll 1
    for (int ci = 0; ci < 8; ++ci) {
        const float* base = h1p + ((n * 8 + ci) * 66 + 2 * y) * 66 + 2 * x;
        #pragma unroll
        for (int ky = 0; ky < 4; ++ky) {
            F4 v = *(const F4*)(base + ky * 66);
            float vv[4] = { v.x, v.y, v.z, v.w };
            #pragma unroll
            for (int kx = 0; kx < 4; ++kx) {
                const float* wp = &wl[((ci * 4 + ky) * 4 + kx) * 4];
                acc[0] = fmaf(vv[kx], wp[0], acc[0]);
                acc[1] = fmaf(vv[kx], wp[1], acc[1]);
                acc[2] = fmaf(vv[kx], wp[2], acc[2]);
                acc[3] = fmaf(vv[kx], wp[3], acc[3]);
            }
        }
    }
    #pragma unroll
    for (int j = 0; j < 4; ++j)
        h2p[((n * 16 + cg * 4 + j) * 34 + y + 1) * 34 + x + 1] = leakyf(acc[j]);
}

// ---------- e3: 16->16, K3 S1 P1, COB4; writes UNPADDED h3 ----------
__global__ __launch_bounds__(256) void e3p_k(const float* __restrict__ h2p,
                                             const float* __restrict__ ew3,
                                             const float* __restrict__ eb3,
                                             float* __restrict__ h3)
{
    __shared__ float wl[576];
    int t = threadIdx.x;
    int id = blockIdx.x * 256 + t;                 // 262144
    int x = id & 31, y = (id >> 5) & 31;
    int cg = rfl((id >> 10) & 3), n = id >> 12;
    for (int i = t; i < 576; i += 256) {
        int co = i & 3, r = i >> 2;
        int kx = r % 3, ky = (r / 3) % 3, ci = r / 9;
        wl[i] = ew3[((cg * 4 + co) * 16 + ci) * 9 + ky * 3 + kx];
    }
    __syncthreads();
    float acc[4];
    #pragma unroll
    for (int j = 0; j < 4; ++j) acc[j] = eb3[cg * 4 + j];
    #pragma unroll 1
    for (int ci = 0; ci < 16; ++ci) {
        const float* base = h2p + ((n * 16 + ci) * 34 + y) * 34 + x;
        #pragma unroll
        for (int ky = 0; ky < 3; ++ky) {
            F4 v = *(const F4*)(base + ky * 34);
            float vv[3] = { v.x, v.y, v.z };
            #pragma unroll
            for (int kx = 0; kx < 3; ++kx) {
                const float* wp = &wl[((ci * 3 + ky) * 3 + kx) * 4];
                acc[0] = fmaf(vv[kx], wp[0], acc[0]);
                acc[1] = fmaf(vv[kx], wp[1], acc[1]);
                acc[2] = fmaf(vv[kx], wp[2], acc[2]);
                acc[3] = fmaf(vv[kx], wp[3], acc[3]);
            }
        }
    }
    #pragma unroll
    for (int j = 0; j < 4; ++j)
        h3[((n * 16 + cg * 4 + j) << 10) + (y << 5) + x] = leakyf(acc[j]);
}

// ---------- fused e4 + VQ: 16x16 register tile, 1 block/CU ----------
// Block = 256 rows x 512 codes (2 panels of 256). Fs[d][row] + Cs[d][code],
// 64 KB each (128 KB LDS). Per d per wave: 8 ds_read_b128 (2-way free) ->
// 256 fma: VALU-bound (512 VALU-cy vs 384 DS-cy per d per CU).
// Thread rows/codes = {tr*4+i + 64g} so reads stay 16B-strided.
__global__ __launch_bounds__(256)
__attribute__((amdgpu_waves_per_eu(1, 1)))
void vqk_k(const float* __restrict__ h3,
           const float* __restrict__ w4t,
           const float* __restrict__ eb4,
           const float* __restrict__ cb,
           const float* __restrict__ c2,
           int* __restrict__ idxOut,
           float* __restrict__ lossAcc)
{
    __shared__ float Fs[64 * 256];     // 64 KB [d][row]
    __shared__ float Cs[64 * 256];     // 64 KB [d][code]; aliased for reduction
    int t = threadIdx.x;
    int row0 = blockIdx.x << 8;        // 256 blocks x 256 rows
    int n = blockIdx.x >> 2;
    int pos0 = (blockIdx.x & 3) << 8;

    // ---- stage F = leaky(W4 h3 + b4): thread t -> row t, all 64 d ----
    {
        const float* hp = h3 + (n << 14) + pos0 + t;
        float h[16];
        #pragma unroll
        for (int ci = 0; ci < 16; ++ci) h[ci] = hp[ci << 10];
        #pragma unroll
        for (int q = 0; q < 16; ++q) {
            int d0 = q * 4;
            float a0 = eb4[d0 + 0], a1 = eb4[d0 + 1];
            float a2 = eb4[d0 + 2], a3 = eb4[d0 + 3];
            #pragma unroll
            for (int ci = 0; ci < 16; ++ci) {
                float v = h[ci];
                const float* wp = w4t + (ci << 6) + d0;
                a0 = fmaf(v, wp[0], a0); a1 = fmaf(v, wp[1], a1);
                a2 = fmaf(v, wp[2], a2); a3 = fmaf(v, wp[3], a3);
            }
            Fs[(d0 + 0) * 256 + t] = leakyf(a0);
            Fs[(d0 + 1) * 256 + t] = leakyf(a1);
            Fs[(d0 + 2) * 256 + t] = leakyf(a2);
            Fs[(d0 + 3) * 256 + t] = leakyf(a3);
        }
    }
    // ---- stage C panel 0: thread t -> code t ----
    {
        const float* src = cb + (t << 6);
        #pragma unroll
        for (int q = 0; q < 16; ++q) {
            float4 v = *(const float4*)(src + q * 4);
            Cs[(q * 4 + 0) * 256 + t] = v.x;
            Cs[(q * 4 + 1) * 256 + t] = v.y;
            Cs[(q * 4 + 2) * 256 + t] = v.z;
            Cs[(q * 4 + 3) * 256 + t] = v.w;
        }
    }
    __syncthreads();

    int tr = t & 15, tc = t >> 4;
    float best[16]; int bk[16];
    #pragma unroll
    for (int i = 0; i < 16; ++i) { best[i] = 3.4e38f; bk[i] = 0; }

    #pragma unroll 1
    for (int p = 0; p < 2; ++p) {
        if (p) {
            __syncthreads();           // panel-0 reads done
            const float* src = cb + ((256 + t) << 6);
            #pragma unroll
            for (int q = 0; q < 16; ++q) {
                float4 v = *(const float4*)(src + q * 4);
                Cs[(q * 4 + 0) * 256 + t] = v.x;
                Cs[(q * 4 + 1) * 256 + t] = v.y;
                Cs[(q * 4 + 2) * 256 + t] = v.z;
                Cs[(q * 4 + 3) * 256 + t] = v.w;
            }
            __syncthreads();
        }

        float acc[16][16];
        #pragma unroll
        for (int i = 0; i < 16; ++i)
            #pragma unroll
            for (int j = 0; j < 16; ++j) acc[i][j] = 0.f;

        const float* fb = &Fs[tr * 4];
        const float* cp = &Cs[tc * 4];
        #pragma unroll 2
        for (int d = 0; d < 64; ++d) {
            float4 f0 = *(const float4*)(fb + d * 256);
            float4 f1 = *(const float4*)(fb + d * 256 + 64);
            float4 f2 = *(const float4*)(fb + d * 256 + 128);
            float4 f3 = *(const float4*)(fb + d * 256 + 192);
            float4 c0 = *(const float4*)(cp + d * 256);
            float4 c1 = *(const float4*)(cp + d * 256 + 64);
            float4 c2v = *(const float4*)(cp + d * 256 + 128);
            float4 c3 = *(const float4*)(cp + d * 256 + 192);
            float f[16] = { f0.x, f0.y, f0.z, f0.w, f1.x, f1.y, f1.z, f1.w,
                            f2.x, f2.y, f2.z, f2.w, f3.x, f3.y, f3.z, f3.w };
            float c[16] = { c0.x, c0.y, c0.z, c0.w, c1.x, c1.y, c1.z, c1.w,
                            c2v.x, c2v.y, c2v.z, c2v.w, c3.x, c3.y, c3.z, c3.w };
            #pragma unroll
            for (int i = 0; i < 16; ++i)
                #pragma unroll
                for (int j = 0; j < 16; ++j)
                    acc[i][j] = fmaf(f[i], c[j], acc[i][j]);
        }

        // epilogue: ascending kk within thread (h outer, jj inner), strict <
        #pragma unroll
        for (int h = 0; h < 4; ++h)
            #pragma unroll
            for (int jj = 0; jj < 4; ++jj) {
                int kk = (p << 8) + (h << 6) + tc * 4 + jj;
                float hc2 = 0.5f * c2[kk];
                int j = h * 4 + jj;
                #pragma unroll
                for (int i = 0; i < 16; ++i) {
                    float s = hc2 - acc[i][j];
                    if (s < best[i]) { best[i] = s; bk[i] = kk; }
                }
            }
    }

    __syncthreads();                   // all Cs reads done; alias for reduction
    float* redS = Cs;                  // [row256][17]
    int*   redI = (int*)(Cs + 4352);
    #pragma unroll
    for (int i = 0; i < 16; ++i) {
        int row = ((i >> 2) << 6) + tr * 4 + (i & 3);
        redS[row * 17 + tc] = best[i];
        redI[row * 17 + tc] = bk[i];
    }
    __syncthreads();
    {
        int row = t;
        float bs = redS[row * 17]; int bi = redI[row * 17];
        #pragma unroll
        for (int c = 1; c < 16; ++c) {    // (score, idx) lexicographic = first-min
            float s2 = redS[row * 17 + c];
            int   i2 = redI[row * 17 + c];
            if (s2 < bs || (s2 == bs && i2 < bi)) { bs = s2; bi = i2; }
        }
        idxOut[row0 + row] = bi;
        // loss: sum (cb[bi] - f)^2  (commitment == embedding in fwd)
        const float* cr = cb + (bi << 6);
        float rs = 0.f;
        #pragma unroll
        for (int d = 0; d < 64; ++d) {
            float e = cr[d] - Fs[d * 256 + row];
            rs = fmaf(e, e, rs);
        }
        #pragma unroll
        for (int off = 32; off; off >>= 1) rs += __shfl_down(rs, off, 64);
        if ((t & 63) == 0) atomicAdd(lossAcc, rs);
    }
}

// ---------- d1 via U-table, writes PADDED D1P ----------
__global__ __launch_bounds__(256) void d1p_k(const int* __restrict__ idx,
                                             const float* __restrict__ U,
                                             const float* __restrict__ db1,
                                             float* __restrict__ d1p)
{
    int id = blockIdx.x * 256 + threadIdx.x;       // 262144
    int x = id & 31, y = (id >> 5) & 31;
    int cg = rfl((id >> 10) & 3), n = id >> 12;
    float acc[4];
    #pragma unroll
    for (int j = 0; j < 4; ++j) acc[j] = db1[cg * 4 + j];
    const float4* U4 = (const float4*)U;
    #pragma unroll
    for (int tap = 0; tap < 9; ++tap) {
        int yy = y + tap / 3 - 1, xx = x + tap % 3 - 1;
        if (yy < 0 || yy > 31 || xx < 0 || xx > 31) continue;
        int k = idx[(n << 10) + (yy << 5) + xx];
        float4 u = U4[(k * 9 + tap) * 4 + cg];
        acc[0] += u.x; acc[1] += u.y; acc[2] += u.z; acc[3] += u.w;
    }
    #pragma unroll
    for (int j = 0; j < 4; ++j)
        d1p[((n * 16 + cg * 4 + j) * 34 + y + 1) * 34 + x + 1] = leakyf(acc[j]);
}

// ---------- dt2: ConvT 16->8 K4 S2 P1, parity form, COB2 ----------
__global__ __launch_bounds__(256) void dt2p_k(const float* __restrict__ d1p,
                                              const float* __restrict__ dw2,
                                              const float* __restrict__ db2,
                                              float* __restrict__ d2p)
{
    __shared__ float wl[512];
    int t = threadIdx.x;
    int id = blockIdx.x * 256 + t;                 // 262144
    int x = id & 31, y = (id >> 5) & 31;
    int cg = rfl((id >> 10) & 3), n = id >> 12;
    for (int i = t; i < 512; i += 256) {
        int co = i & 1, tap = (i >> 1) & 15, ci = i >> 5;
        wl[i] = dw2[(ci * 8 + cg * 2 + co) * 16 + tap];
    }
    __syncthreads();
    float acc[2][2][2];
    #pragma unroll
    for (int py = 0; py < 2; ++py)
        #pragma unroll
        for (int px = 0; px < 2; ++px)
            #pragma unroll
            for (int j = 0; j < 2; ++j) acc[py][px][j] = db2[cg * 2 + j];
    #pragma unroll 1
    for (int ci = 0; ci < 16; ++ci) {
        const float* base = d1p + ((n * 16 + ci) * 34 + y) * 34 + x;
        F4 r0 = *(const F4*)(base);
        F4 r1 = *(const F4*)(base + 34);
        F4 r2 = *(const F4*)(base + 68);
        float v[3][3] = { { r0.x, r0.y, r0.z },
                          { r1.x, r1.y, r1.z },
                          { r2.x, r2.y, r2.z } };
        #pragma unroll
        for (int ky = 0; ky < 4; ++ky) {
            int py = (ky + 1) & 1;
            int dy = (ky == 0) ? 1 : (ky == 3 ? -1 : 0);
            #pragma unroll
            for (int kx = 0; kx < 4; ++kx) {
                int px = (kx + 1) & 1;
                int dx = (kx == 0) ? 1 : (kx == 3 ? -1 : 0);
                float vv = v[dy + 1][dx + 1];
                const float* wp = &wl[(ci * 16 + ky * 4 + kx) * 2];
                acc[py][px][0] = fmaf(vv, wp[0], acc[py][px][0]);
                acc[py][px][1] = fmaf(vv, wp[1], acc[py][px][1]);
            }
        }
    }
    #pragma unroll
    for (int py = 0; py < 2; ++py)
        #pragma unroll
        for (int px = 0; px < 2; ++px)
            #pragma unroll
            for (int j = 0; j < 2; ++j)
                d2p[((n * 8 + cg * 2 + j) * 66 + 2 * y + py + 1) * 66 + 2 * x + px + 1] =
                    leakyf(acc[py][px][j]);
}

// ---------- dt3: ConvT 8->1 K4 S2 P1, parity form, tanh ----------
__global__ __launch_bounds__(256) void dt3p_k(const float* __restrict__ d2p,
                                              const float* __restrict__ dw3,
                                              const float* __restrict__ db3,
                                              float* __restrict__ out)
{
    int id = blockIdx.x * 256 + threadIdx.x;       // 262144
    int x = id & 63, y = (id >> 6) & 63, n = id >> 12;
    float b = db3[0];
    float acc[2][2] = { { b, b }, { b, b } };
    #pragma unroll 1
    for (int ci = 0; ci < 8; ++ci) {
        const float* base = d2p + ((n * 8 + ci) * 66 + y) * 66 + x;
        F4 r0 = *(const F4*)(base);
        F4 r1 = *(const F4*)(base + 66);
        F4 r2 = *(const F4*)(base + 132);
        float v[3][3] = { { r0.x, r0.y, r0.z },
                          { r1.x, r1.y, r1.z },
                          { r2.x, r2.y, r2.z } };
        #pragma unroll
        for (int ky = 0; ky < 4; ++ky) {
            int py = (ky + 1) & 1;
            int dy = (ky == 0) ? 1 : (ky == 3 ? -1 : 0);
            #pragma unroll
            for (int kx = 0; kx < 4; ++kx) {
                int px = (kx + 1) & 1;
                int dx = (kx == 0) ? 1 : (kx == 3 ? -1 : 0);
                acc[py][px] = fmaf(v[dy + 1][dx + 1], dw3[ci * 16 + ky * 4 + kx],
                                   acc[py][px]);
            }
        }
    }
    #pragma unroll
    for (int py = 0; py < 2; ++py)
        #pragma unroll
        for (int px = 0; px < 2; ++px)
            out[(n << 14) + ((2 * y + py) << 7) + 2 * x + px] = tanhf(acc[py][px]);
}

__global__ void loss_k(const float* __restrict__ acc, float* __restrict__ out)
{
    out[0] = 1.25f * acc[0] / 4194304.0f;
}

extern "C" void kernel_launch(void* const* d_in, const int* in_sizes, int n_in,
                              void* d_out, int out_size, void* d_ws, size_t ws_size,
                              hipStream_t stream)
{
    const float* x        = (const float*)d_in[0];
    const float* ew1      = (const float*)d_in[1];
    const float* eb1      = (const float*)d_in[2];
    const float* ew2      = (const float*)d_in[3];
    const float* eb2      = (const float*)d_in[4];
    const float* ew3      = (const float*)d_in[5];
    const float* eb3      = (const float*)d_in[6];
    const float* ew4      = (const float*)d_in[7];
    const float* eb4      = (const float*)d_in[8];
    const float* codebook = (const float*)d_in[9];
    const float* dw1      = (const float*)d_in[10];
    const float* db1      = (const float*)d_in[11];
    const float* dw2      = (const float*)d_in[12];
    const float* db2      = (const float*)d_in[13];
    const float* dw3      = (const float*)d_in[14];
    const float* db3      = (const float*)d_in[15];

    float* out = (float*)d_out;
    float* ws  = (float*)d_ws;
    float* XP   = ws + OFF_XP;
    float* H1P  = ws + OFF_H1P;
    float* H2P  = ws + OFF_H2P;
    float* H3   = ws + OFF_H3;
    float* D1P  = ws + OFF_D1P;
    float* D2P  = ws + OFF_D2P;
    int*   IDX  = (int*)(ws + OFF_IDX);
    float* U    = ws + OFF_U;
    float* C2   = ws + OFF_C2;
    float* W4T  = ws + OFF_W4T;
    float* DWT  = ws + OFF_DWT;
    float* LOSS = ws + OFF_LOSS;

    prep_k<<<42, 256, 0, stream>>>(ew4, dw1, codebook, ws);
    uprep_k<<<288, 256, 0, stream>>>(DWT, codebook, U);
    setup2_k<<<4096, 256, 0, stream>>>(x, ws);

    e1p_k<<<1024, 256, 0, stream>>>(XP, ew1, eb1, H1P);
    e2p_k<<<1024, 256, 0, stream>>>(H1P, ew2, eb2, H2P);
    e3p_k<<<1024, 256, 0, stream>>>(H2P, ew3, eb3, H3);

    vqk_k<<<256, 256, 0, stream>>>(H3, W4T, eb4, codebook, C2, IDX, LOSS);

    d1p_k<<<1024, 256, 0, stream>>>(IDX, U, db1, D1P);
    dt2p_k<<<1024, 256, 0, stream>>>(D1P, dw2, db2, D2P);
    dt3p_k<<<1024, 256, 0, stream>>>(D2P, dw3, db3, out);

    loss_k<<<1, 1, 0, stream>>>(LOSS, out + 1048576);
}

// Round 14
// 133.967 us; speedup vs baseline: 1.4569x; 1.4569x over previous
//
#include <hip/hip_runtime.h>
#include <math.h>

#define DEV __device__ __forceinline__
DEV float leakyf(float v) { return v >= 0.f ? v : 0.01f * v; }
DEV int rfl(int v) { return __builtin_amdgcn_readfirstlane(v); }

struct F4 { float x, y, z, w; };   // natural align 4: legal on any float*

// ---- ws layout (float offsets) ----
#define OFF_XP   0u          // x padded [64][130][130]      1081600
#define OFF_H1P  1081600u    // h1 [64][8][66][66]           2230272
#define OFF_H2P  3311872u    // h2 [64][16][34][34]          1183744
#define OFF_H3   4495616u    // h3 [64][16][32][32]          1048576
#define OFF_D1P  5544192u    // d1 [64][16][34][34]          1183744
#define OFF_D2P  6727936u    // d2 [64][8][66][66]           2230272
#define OFF_IDX  8958208u    // 65536 int32
#define OFF_U    9023744u    // 73728 [k512][tap9][co16]
#define OFF_C2   9097472u    // 512
#define OFF_W4T  9097984u    // 1024 [ci16][d64]
#define OFF_DWT  9099008u    // 9216 [ci64][tap9*16+co16]
#define OFF_LOSS 9108224u    // 1 (+pad)

// ---------- halo zeroing helper ----------
DEV void halo_store(float* base, int plane, int r, int W, int H, long psz)
{
    int row, col;
    if (r < W)          { row = 0;     col = r; }
    else if (r < 2 * W) { row = H - 1; col = r - W; }
    else { int r2 = r - 2 * W; row = 1 + (r2 >> 1); col = (r2 & 1) ? W - 1 : 0; }
    base[plane * psz + row * W + col] = 0.f;
}

// ---------- setup: x pad + halos + W4T + C2 + DWT + LOSS zero, one kernel ----
__global__ void setup_k(const float* __restrict__ x, const float* __restrict__ ew4,
                        const float* __restrict__ dw1, const float* __restrict__ cb,
                        float* __restrict__ ws)
{
    int id = blockIdx.x * 256 + threadIdx.x;       // 1048576
    // pad x interior (all ids)
    {
        int ix = id & 127, iy = (id >> 7) & 127, n = id >> 14;
        ws[OFF_XP + (n * 130 + iy + 1) * 130 + ix + 1] = x[id];
    }
    // halos (disjoint cells)
    if (id < 33024) {
        halo_store(ws + OFF_XP, id / 516, id % 516, 130, 130, 16900);
    } else if (id < 166144) {
        int i = id - 33024;
        halo_store(ws + OFF_H1P, i / 260, i % 260, 66, 66, 4356);
    } else if (id < 301312) {
        int i = id - 166144;
        halo_store(ws + OFF_H2P, i / 132, i % 132, 34, 34, 1156);
    } else if (id < 436480) {
        int i = id - 301312;
        halo_store(ws + OFF_D1P, i / 132, i % 132, 34, 34, 1156);
    } else if (id < 569600) {
        int i = id - 436480;
        halo_store(ws + OFF_D2P, i / 260, i % 260, 66, 66, 4356);
    }
    // prep tasks folded in (small id ranges, distinct buffers)
    if (id < 1024) {                               // W4T: [ci*64+d] = ew4[d][ci]
        int d = id & 63, ci = id >> 6;
        ws[OFF_W4T + id] = ew4[d * 16 + ci];
    } else if (id < 1536) {                        // C2
        int k = id - 1024;
        float s = 0.f;
        #pragma unroll
        for (int d = 0; d < 64; ++d) { float v = cb[k * 64 + d]; s = fmaf(v, v, s); }
        ws[OFF_C2 + k] = s;
    } else if (id == 1536) {
        ws[OFF_LOSS] = 0.f;
    } else if (id >= 2048 && id < 11264) {         // DWT: [ci*144+tap*16+co]
        int i = id - 2048;
        int co = i & 15, tap = (i >> 4) % 9, ci = i / 144;
        ws[OFF_DWT + i] = dw1[(co * 64 + ci) * 9 + tap];
    }
}

// U[k][tap][co] = sum_ci dwT[ci][tap*16+co] * cb[k][ci]
__global__ void uprep_k(const float* __restrict__ dwT, const float* __restrict__ cb,
                        float* __restrict__ U)
{
    int id = blockIdx.x * 256 + threadIdx.x;   // 73728
    int k = id / 144;
    int r = id - k * 144;
    float s = 0.f;
    #pragma unroll
    for (int ci = 0; ci < 64; ++ci)
        s = fmaf(cb[k * 64 + ci], dwT[ci * 144 + r], s);
    U[id] = s;
}

// ---------- e1: 1->8, K4 S2 P1 ----------
__global__ __launch_bounds__(256) void e1p_k(const float* __restrict__ xp,
                                             const float* __restrict__ ew1,
                                             const float* __restrict__ eb1,
                                             float* __restrict__ h1p)
{
    __shared__ float wl[128];
    int t = threadIdx.x;
    if (t < 128) { int co = t & 7, tap = t >> 3; wl[t] = ew1[co * 16 + tap]; }
    __syncthreads();
    int id = blockIdx.x * 256 + t;                 // 262144
    int x = id & 63, y = (id >> 6) & 63, n = id >> 12;
    float acc[8];
    #pragma unroll
    for (int j = 0; j < 8; ++j) acc[j] = eb1[j];
    const float* base = xp + (n * 130 + 2 * y) * 130 + 2 * x;
    #pragma unroll
    for (int ky = 0; ky < 4; ++ky) {
        F4 v = *(const F4*)(base + ky * 130);
        float vv[4] = { v.x, v.y, v.z, v.w };
        #pragma unroll
        for (int kx = 0; kx < 4; ++kx) {
            const float* wp = &wl[(ky * 4 + kx) * 8];
            #pragma unroll
            for (int j = 0; j < 8; ++j) acc[j] = fmaf(vv[kx], wp[j], acc[j]);
        }
    }
    #pragma unroll
    for (int j = 0; j < 8; ++j)
        h1p[((n * 8 + j) * 66 + y + 1) * 66 + x + 1] = leakyf(acc[j]);
}

// ---------- e2: 8->16, K4 S2 P1, COB4 ----------
__global__ __launch_bounds__(256) void e2p_k(const float* __restrict__ h1p,
                                             const float* __restrict__ ew2,
                                             const float* __restrict__ eb2,
                                             float* __restrict__ h2p)
{
    __shared__ float wl[512];
    int t = threadIdx.x;
    int id = blockIdx.x * 256 + t;                 // 262144
    int x = id & 31, y = (id >> 5) & 31;
    int cg = rfl((id >> 10) & 3), n = id >> 12;
    for (int i = t; i < 512; i += 256) {
        int co = i & 3, r = i >> 2;
        int kx = r & 3, ky = (r >> 2) & 3, ci = r >> 4;
        wl[i] = ew2[((cg * 4 + co) * 8 + ci) * 16 + ky * 4 + kx];
    }
    __syncthreads();
    float acc[4];
    #pragma unroll
    for (int j = 0; j < 4; ++j) acc[j] = eb2[cg * 4 + j];
    #pragma unroll 1
    for (int ci = 0; ci < 8; ++ci) {
        const float* base = h1p + ((n * 8 + ci) * 66 + 2 * y) * 66 + 2 * x;
        #pragma unroll
        for (int ky = 0; ky < 4; ++ky) {
            F4 v = *(const F4*)(base + ky * 66);
            float vv[4] = { v.x, v.y, v.z, v.w };
            #pragma unroll
            for (int kx = 0; kx < 4; ++kx) {
                const float* wp = &wl[((ci * 4 + ky) * 4 + kx) * 4];
                acc[0] = fmaf(vv[kx], wp[0], acc[0]);
                acc[1] = fmaf(vv[kx], wp[1], acc[1]);
                acc[2] = fmaf(vv[kx], wp[2], acc[2]);
                acc[3] = fmaf(vv[kx], wp[3], acc[3]);
            }
        }
    }
    #pragma unroll
    for (int j = 0; j < 4; ++j)
        h2p[((n * 16 + cg * 4 + j) * 34 + y + 1) * 34 + x + 1] = leakyf(acc[j]);
}

// ---------- e3: 16->16, K3 S1 P1, COB4; writes UNPADDED h3 ----------
__global__ __launch_bounds__(256) void e3p_k(const float* __restrict__ h2p,
                                             const float* __restrict__ ew3,
                                             const float* __restrict__ eb3,
                                             float* __restrict__ h3)
{
    __shared__ float wl[576];
    int t = threadIdx.x;
    int id = blockIdx.x * 256 + t;                 // 262144
    int x = id & 31, y = (id >> 5) & 31;
    int cg = rfl((id >> 10) & 3), n = id >> 12;
    for (int i = t; i < 576; i += 256) {
        int co = i & 3, r = i >> 2;
        int kx = r % 3, ky = (r / 3) % 3, ci = r / 9;
        wl[i] = ew3[((cg * 4 + co) * 16 + ci) * 9 + ky * 3 + kx];
    }
    __syncthreads();
    float acc[4];
    #pragma unroll
    for (int j = 0; j < 4; ++j) acc[j] = eb3[cg * 4 + j];
    #pragma unroll 1
    for (int ci = 0; ci < 16; ++ci) {
        const float* base = h2p + ((n * 16 + ci) * 34 + y) * 34 + x;
        #pragma unroll
        for (int ky = 0; ky < 3; ++ky) {
            F4 v = *(const F4*)(base + ky * 34);
            float vv[3] = { v.x, v.y, v.z };
            #pragma unroll
            for (int kx = 0; kx < 3; ++kx) {
                const float* wp = &wl[((ci * 3 + ky) * 3 + kx) * 4];
                acc[0] = fmaf(vv[kx], wp[0], acc[0]);
                acc[1] = fmaf(vv[kx], wp[1], acc[1]);
                acc[2] = fmaf(vv[kx], wp[2], acc[2]);
                acc[3] = fmaf(vv[kx], wp[3], acc[3]);
            }
        }
    }
    #pragma unroll
    for (int j = 0; j < 4; ++j)
        h3[((n * 16 + cg * 4 + j) << 10) + (y << 5) + x] = leakyf(acc[j]);
}

// ---------- fused e4 + VQ, d-major LDS GEMM (r9-proven best: 76 us) ----------
__global__ __launch_bounds__(256) void vqh_k(const float* __restrict__ h3,
                                             const float* __restrict__ w4t,
                                             const float* __restrict__ eb4,
                                             const float* __restrict__ cb,
                                             const float* __restrict__ c2,
                                             int* __restrict__ idxOut,
                                             float* __restrict__ lossAcc)
{
    __shared__ float Fs[64 * 128];
    __shared__ float Cs[64 * 128];
    int t = threadIdx.x;
    int row0 = blockIdx.x << 7;
    int n = row0 >> 10;
    int pos0 = row0 & 1023;

    {
        int row = t & 127, dh = t >> 7;
        const float* hp = h3 + (n << 14) + pos0 + row;
        float h[16];
        #pragma unroll
        for (int ci = 0; ci < 16; ++ci) h[ci] = hp[ci << 10];
        #pragma unroll
        for (int q = 0; q < 8; ++q) {
            int d0 = dh * 32 + q * 4;
            float a0 = eb4[d0 + 0], a1 = eb4[d0 + 1];
            float a2 = eb4[d0 + 2], a3 = eb4[d0 + 3];
            #pragma unroll
            for (int ci = 0; ci < 16; ++ci) {
                float v = h[ci];
                const float* wp = w4t + (ci << 6) + d0;
                a0 = fmaf(v, wp[0], a0); a1 = fmaf(v, wp[1], a1);
                a2 = fmaf(v, wp[2], a2); a3 = fmaf(v, wp[3], a3);
            }
            Fs[(d0 + 0) * 128 + row] = leakyf(a0);
            Fs[(d0 + 1) * 128 + row] = leakyf(a1);
            Fs[(d0 + 2) * 128 + row] = leakyf(a2);
            Fs[(d0 + 3) * 128 + row] = leakyf(a3);
        }
    }

    int tr = t & 15, tc = t >> 4;
    float best[8]; int bk[8];
    #pragma unroll
    for (int i = 0; i < 8; ++i) { best[i] = 3.4e38f; bk[i] = 0; }

    #pragma unroll 1
    for (int p = 0; p < 4; ++p) {
        __syncthreads();
        {
            int code = t >> 1, dh = t & 1;
            const float* src = cb + (((p << 7) + code) << 6) + dh * 32;
            #pragma unroll
            for (int q = 0; q < 8; ++q) {
                float4 v = *(const float4*)(src + q * 4);
                int d0 = dh * 32 + q * 4;
                Cs[(d0 + 0) * 128 + code] = v.x;
                Cs[(d0 + 1) * 128 + code] = v.y;
                Cs[(d0 + 2) * 128 + code] = v.z;
                Cs[(d0 + 3) * 128 + code] = v.w;
            }
        }
        __syncthreads();

        float acc[8][8];
        #pragma unroll
        for (int i = 0; i < 8; ++i)
            #pragma unroll
            for (int j = 0; j < 8; ++j) acc[i][j] = 0.f;

        const float* fp0 = &Fs[tr * 4];
        const float* fp1 = &Fs[64 + tr * 4];
        const float* cp0 = &Cs[tc * 4];
        const float* cp1 = &Cs[64 + tc * 4];
        #pragma unroll 8
        for (int d = 0; d < 64; ++d) {
            float4 f0 = *(const float4*)(fp0 + d * 128);
            float4 f1 = *(const float4*)(fp1 + d * 128);
            float4 c0 = *(const float4*)(cp0 + d * 128);
            float4 c1 = *(const float4*)(cp1 + d * 128);
            float f[8] = { f0.x, f0.y, f0.z, f0.w, f1.x, f1.y, f1.z, f1.w };
            float c[8] = { c0.x, c0.y, c0.z, c0.w, c1.x, c1.y, c1.z, c1.w };
            #pragma unroll
            for (int i = 0; i < 8; ++i)
                #pragma unroll
                for (int j = 0; j < 8; ++j)
                    acc[i][j] = fmaf(f[i], c[j], acc[i][j]);
        }
        #pragma unroll
        for (int j = 0; j < 8; ++j) {
            int kk = (p << 7) + (j < 4 ? tc * 4 + j : 64 + tc * 4 + j - 4);
            float hc2 = 0.5f * c2[kk];
            #pragma unroll
            for (int i = 0; i < 8; ++i) {
                float s = hc2 - acc[i][j];
                if (s < best[i]) { best[i] = s; bk[i] = kk; }
            }
        }
    }

    __syncthreads();
    float* redS = Cs;
    int*   redI = (int*)(Cs + 2176);
    #pragma unroll
    for (int i = 0; i < 8; ++i) {
        int row = (i < 4) ? tr * 4 + i : 64 + tr * 4 + i - 4;
        redS[row * 17 + tc] = best[i];
        redI[row * 17 + tc] = bk[i];
    }
    __syncthreads();
    if (t < 128) {
        int row = t;
        float bs = redS[row * 17]; int bi = redI[row * 17];
        #pragma unroll
        for (int c = 1; c < 16; ++c) {
            float s2 = redS[row * 17 + c];
            int   i2 = redI[row * 17 + c];
            if (s2 < bs || (s2 == bs && i2 < bi)) { bs = s2; bi = i2; }
        }
        idxOut[row0 + row] = bi;
        const float* cr = cb + (bi << 6);
        float rs = 0.f;
        #pragma unroll
        for (int d = 0; d < 64; ++d) {
            float e = cr[d] - Fs[d * 128 + row];
            rs = fmaf(e, e, rs);
        }
        #pragma unroll
        for (int off = 32; off; off >>= 1) rs += __shfl_down(rs, off, 64);
        if ((t & 63) == 0) atomicAdd(lossAcc, rs);
    }
}

// ---------- d1 via U-table, writes PADDED D1P; finalizes loss ----------
__global__ __launch_bounds__(256) void d1p_k(const int* __restrict__ idx,
                                             const float* __restrict__ U,
                                             const float* __restrict__ db1,
                                             const float* __restrict__ lossAcc,
                                             float* __restrict__ lossOut,
                                             float* __restrict__ d1p)
{
    int id = blockIdx.x * 256 + threadIdx.x;       // 262144
    if (id == 0) lossOut[0] = 1.25f * lossAcc[0] / 4194304.0f;
    int x = id & 31, y = (id >> 5) & 31;
    int cg = rfl((id >> 10) & 3), n = id >> 12;
    float acc[4];
    #pragma unroll
    for (int j = 0; j < 4; ++j) acc[j] = db1[cg * 4 + j];
    const float4* U4 = (const float4*)U;
    #pragma unroll
    for (int tap = 0; tap < 9; ++tap) {
        int yy = y + tap / 3 - 1, xx = x + tap % 3 - 1;
        if (yy < 0 || yy > 31 || xx < 0 || xx > 31) continue;
        int k = idx[(n << 10) + (yy << 5) + xx];
        float4 u = U4[(k * 9 + tap) * 4 + cg];
        acc[0] += u.x; acc[1] += u.y; acc[2] += u.z; acc[3] += u.w;
    }
    #pragma unroll
    for (int j = 0; j < 4; ++j)
        d1p[((n * 16 + cg * 4 + j) * 34 + y + 1) * 34 + x + 1] = leakyf(acc[j]);
}

// ---------- dt2: ConvT 16->8 K4 S2 P1, parity form, COB2 ----------
__global__ __launch_bounds__(256) void dt2p_k(const float* __restrict__ d1p,
                                              const float* __restrict__ dw2,
                                              const float* __restrict__ db2,
                                              float* __restrict__ d2p)
{
    __shared__ float wl[512];
    int t = threadIdx.x;
    int id = blockIdx.x * 256 + t;                 // 262144
    int x = id & 31, y = (id >> 5) & 31;
    int cg = rfl((id >> 10) & 3), n = id >> 12;
    for (int i = t; i < 512; i += 256) {
        int co = i & 1, tap = (i >> 1) & 15, ci = i >> 5;
        wl[i] = dw2[(ci * 8 + cg * 2 + co) * 16 + tap];
    }
    __syncthreads();
    float acc[2][2][2];
    #pragma unroll
    for (int py = 0; py < 2; ++py)
        #pragma unroll
        for (int px = 0; px < 2; ++px)
            #pragma unroll
            for (int j = 0; j < 2; ++j) acc[py][px][j] = db2[cg * 2 + j];
    #pragma unroll 1
    for (int ci = 0; ci < 16; ++ci) {
        const float* base = d1p + ((n * 16 + ci) * 34 + y) * 34 + x;
        F4 r0 = *(const F4*)(base);
        F4 r1 = *(const F4*)(base + 34);
        F4 r2 = *(const F4*)(base + 68);
        float v[3][3] = { { r0.x, r0.y, r0.z },
                          { r1.x, r1.y, r1.z },
                          { r2.x, r2.y, r2.z } };
        #pragma unroll
        for (int ky = 0; ky < 4; ++ky) {
            int py = (ky + 1) & 1;
            int dy = (ky == 0) ? 1 : (ky == 3 ? -1 : 0);
            #pragma unroll
            for (int kx = 0; kx < 4; ++kx) {
                int px = (kx + 1) & 1;
                int dx = (kx == 0) ? 1 : (kx == 3 ? -1 : 0);
                float vv = v[dy + 1][dx + 1];
                const float* wp = &wl[(ci * 16 + ky * 4 + kx) * 2];
                acc[py][px][0] = fmaf(vv, wp[0], acc[py][px][0]);
                acc[py][px][1] = fmaf(vv, wp[1], acc[py][px][1]);
            }
        }
    }
    #pragma unroll
    for (int py = 0; py < 2; ++py)
        #pragma unroll
        for (int px = 0; px < 2; ++px)
            #pragma unroll
            for (int j = 0; j < 2; ++j)
                d2p[((n * 8 + cg * 2 + j) * 66 + 2 * y + py + 1) * 66 + 2 * x + px + 1] =
                    leakyf(acc[py][px][j]);
}

// ---------- dt3: ConvT 8->1 K4 S2 P1, parity form, tanh ----------
__global__ __launch_bounds__(256) void dt3p_k(const float* __restrict__ d2p,
                                              const float* __restrict__ dw3,
                                              const float* __restrict__ db3,
                                              float* __restrict__ out)
{
    int id = blockIdx.x * 256 + threadIdx.x;       // 262144
    int x = id & 63, y = (id >> 6) & 63, n = id >> 12;
    float b = db3[0];
    float acc[2][2] = { { b, b }, { b, b } };
    #pragma unroll 1
    for (int ci = 0; ci < 8; ++ci) {
        const float* base = d2p + ((n * 8 + ci) * 66 + y) * 66 + x;
        F4 r0 = *(const F4*)(base);
        F4 r1 = *(const F4*)(base + 66);
        F4 r2 = *(const F4*)(base + 132);
        float v[3][3] = { { r0.x, r0.y, r0.z },
                          { r1.x, r1.y, r1.z },
                          { r2.x, r2.y, r2.z } };
        #pragma unroll
        for (int ky = 0; ky < 4; ++ky) {
            int py = (ky + 1) & 1;
            int dy = (ky == 0) ? 1 : (ky == 3 ? -1 : 0);
            #pragma unroll
            for (int kx = 0; kx < 4; ++kx) {
                int px = (kx + 1) & 1;
                int dx = (kx == 0) ? 1 : (kx == 3 ? -1 : 0);
                acc[py][px] = fmaf(v[dy + 1][dx + 1], dw3[ci * 16 + ky * 4 + kx],
                                   acc[py][px]);
            }
        }
    }
    #pragma unroll
    for (int py = 0; py < 2; ++py)
        #pragma unroll
        for (int px = 0; px < 2; ++px)
            out[(n << 14) + ((2 * y + py) << 7) + 2 * x + px] = tanhf(acc[py][px]);
}

extern "C" void kernel_launch(void* const* d_in, const int* in_sizes, int n_in,
                              void* d_out, int out_size, void* d_ws, size_t ws_size,
                              hipStream_t stream)
{
    const float* x        = (const float*)d_in[0];
    const float* ew1      = (const float*)d_in[1];
    const float* eb1      = (const float*)d_in[2];
    const float* ew2      = (const float*)d_in[3];
    const float* eb2      = (const float*)d_in[4];
    const float* ew3      = (const float*)d_in[5];
    const float* eb3      = (const float*)d_in[6];
    const float* ew4      = (const float*)d_in[7];
    const float* eb4      = (const float*)d_in[8];
    const float* codebook = (const float*)d_in[9];
    const float* dw1      = (const float*)d_in[10];
    const float* db1      = (const float*)d_in[11];
    const float* dw2      = (const float*)d_in[12];
    const float* db2      = (const float*)d_in[13];
    const float* dw3      = (const float*)d_in[14];
    const float* db3      = (const float*)d_in[15];

    float* out = (float*)d_out;
    float* ws  = (float*)d_ws;
    float* XP   = ws + OFF_XP;
    float* H1P  = ws + OFF_H1P;
    float* H2P  = ws + OFF_H2P;
    float* H3   = ws + OFF_H3;
    float* D1P  = ws + OFF_D1P;
    float* D2P  = ws + OFF_D2P;
    int*   IDX  = (int*)(ws + OFF_IDX);
    float* U    = ws + OFF_U;
    float* C2   = ws + OFF_C2;
    float* W4T  = ws + OFF_W4T;
    float* DWT  = ws + OFF_DWT;
    float* LOSS = ws + OFF_LOSS;

    setup_k<<<4096, 256, 0, stream>>>(x, ew4, dw1, codebook, ws);
    uprep_k<<<288, 256, 0, stream>>>(DWT, codebook, U);

    e1p_k<<<1024, 256, 0, stream>>>(XP, ew1, eb1, H1P);
    e2p_k<<<1024, 256, 0, stream>>>(H1P, ew2, eb2, H2P);
    e3p_k<<<1024, 256, 0, stream>>>(H2P, ew3, eb3, H3);

    vqh_k<<<512, 256, 0, stream>>>(H3, W4T, eb4, codebook, C2, IDX, LOSS);

    d1p_k<<<1024, 256, 0, stream>>>(IDX, U, db1, LOSS, out + 1048576, D1P);
    dt2p_k<<<1024, 256, 0, stream>>>(D1P, dw2, db2, D2P);
    dt3p_k<<<1024, 256, 0, stream>>>(D2P, dw3, db3, out);
}